// Round 12
// baseline (164.067 us; speedup 1.0000x reference)
//
#include <hip/hip_runtime.h>

// MetaBaseline: B,Q,WAY,SHOT,H,W,C = 2,75,5,5,10,10,640; k=5
#define QN    75
#define HWN   100
#define CN    640
#define NSUP  500                      // support descriptors per (b, group)
#define MROWS 7500                     // query patches per batch
#define NQD   (2 * MROWS)              // 15000
#define NSD   5000
#define NDESC (NQD + NSD)              // 20000
#define MT    128                      // rows per workgroup
#define NT    256                      // cols per workgroup (split-N: 2 chunks)
#define BK    32                       // K-chunk (20 iterations, double-buffered)
#define CST   272                      // epilogue C stride (dwords); 272%32==16 -> 2-way scan

typedef __attribute__((ext_vector_type(8))) __bf16 bf16x8;
typedef __attribute__((ext_vector_type(4))) float  f32x4;

// async global->LDS DMA, 16B per lane; LDS dest = wave-uniform base + lane*16
#define GLDS(gp, lp) __builtin_amdgcn_global_load_lds(                        \
    (const __attribute__((address_space(1))) void*)(gp),                      \
    (__attribute__((address_space(3))) void*)(lp), 16, 0, 0)

static __device__ inline unsigned short f2bf(float f) {
    unsigned int u = __float_as_uint(f);
    u += 0x7fffu + ((u >> 16) & 1u);        // RNE
    return (unsigned short)(u >> 16);
}

// ---------------------------------------------------------------------------
// Prep (fused, R6 version): one wave per descriptor, inv-norm, bf16 -> ws.
// ---------------------------------------------------------------------------
__global__ __launch_bounds__(256) void prep_kernel(const float* __restrict__ q,
                                                   const float* __restrict__ s,
                                                   unsigned short* __restrict__ qbf,
                                                   unsigned short* __restrict__ sbf) {
    int wave = (blockIdx.x * 256 + threadIdx.x) >> 6;
    int lane = threadIdx.x & 63;
    if (wave >= NDESC) return;
    const float* src = (wave < NQD) ? (q + (size_t)wave * CN)
                                    : (s + (size_t)(wave - NQD) * CN);
    unsigned short* dst = (wave < NQD) ? (qbf + (size_t)wave * CN)
                                       : (sbf + (size_t)(wave - NQD) * CN);
    float4 v[3];
    float ss = 0.f;
#pragma unroll
    for (int j = 0; j < 3; ++j) {
        int idx4 = lane + 64 * j;
        if (idx4 < CN / 4) {
            v[j] = *(const float4*)(src + idx4 * 4);
            ss = fmaf(v[j].x, v[j].x, ss);
            ss = fmaf(v[j].y, v[j].y, ss);
            ss = fmaf(v[j].z, v[j].z, ss);
            ss = fmaf(v[j].w, v[j].w, ss);
        }
    }
#pragma unroll
    for (int off = 32; off > 0; off >>= 1)
        ss += __shfl_xor(ss, off, 64);
    float inv = rsqrtf(ss);
#pragma unroll
    for (int j = 0; j < 3; ++j) {
        int idx4 = lane + 64 * j;
        if (idx4 < CN / 4) {
            ushort4 o;
            o.x = f2bf(v[j].x * inv);
            o.y = f2bf(v[j].y * inv);
            o.z = f2bf(v[j].z * inv);
            o.w = f2bf(v[j].w * inv);
            *(ushort4*)(dst + idx4 * 4) = o;
        }
    }
}

// ---------------------------------------------------------------------------
// MFMA GEMM (128x256 tile, 512 threads = 8 waves) + per-row top-5 partials.
// R12: SOFTWARE-PIPELINED K-loop. BK=32, double-buffered A+B (2 x 24 KB).
// Per iter: issue DMA(k+1) -> buf[1-p]; compute(buf[p]); __syncthreads().
// The barrier's forced vmcnt(0) now waits on a DMA that had the whole
// compute phase (~700 cyc) to land vs ~300 cyc L2 latency -> ~zero stall.
// (R3-R11 all used [DMA; sync-drain; compute] -- full latency exposed/iter;
// that, not drain count/occupancy/L2-misses, is the 40% idle.)
// XCD-clustered work decode kept from R11 (FETCH 118 -> 24 MB).
// LDS swizzle (BK=32: 4 granules/row): slot s of row r holds source granule
// s ^ ((r>>1)&3); frag reads slot (q_ ^ ((lr>>1)&3)) -> 2-way (free, m136).
// ---------------------------------------------------------------------------
__global__ __launch_bounds__(512, 4) void mfma_kernel(const unsigned short* __restrict__ qbf,
                                                      const unsigned short* __restrict__ sbf,
                                                      float* __restrict__ part) {
    // ---- work decode: grid = 1200 1-D blocks, blockIdx.x & 7 ~ XCD ----
    const int xcd = blockIdx.x & 7;
    const int idx = blockIdx.x >> 3;          // 0..149
    const int b   = xcd >> 2;                 // batch (0/1)
    const int mbq = xcd & 3;                  // M quarter
    const int mbsz = (mbq < 3) ? 15 : 14;     // quarter sizes: 15,15,15,14 (=59)
    if (idx >= 10 * mbsz) return;             // block-uniform early exit
    const int g  = idx / (2 * mbsz);
    const int r_ = idx % (2 * mbsz);
    const int nc = r_ / mbsz;
    const int mb = mbq * 15 + (r_ % mbsz);    // 0..58
    const int bg = b * 5 + g;
    const int r0 = mb * MT;
    const int c0 = nc * NT;

    // buf p at smem + p*24576:  A [128 rows][32 k] 8 KB, B [256 cols][32 k] 16 KB
    __shared__ __align__(16) char smem[49152];
    float* Cst = (float*)smem;                 // epilogue [32][CST] = 34.8 KB

    const int t    = threadIdx.x;
    const int lane = t & 63;
    const int wid  = t >> 6;               // 0..7
    const int h    = wid >> 2;             // row half (0/1)
    const int colq = wid & 3;              // col quarter (0..3)

    const unsigned short* qptr = qbf + (size_t)b * MROWS * CN;              // uniform
    const unsigned short* sptr = sbf + (size_t)(b * 25 + g * 5) * HWN * CN; // uniform

    f32x4 acc[4][4];
#pragma unroll
    for (int mt = 0; mt < 4; ++mt)
#pragma unroll
        for (int nt = 0; nt < 4; ++nt)
            acc[mt][nt] = (f32x4)0.f;

    // ---- staging setup: lane -> (sub-row lane>>2, slot lane&3) of a 1 KB
    // chunk (16 rows x 64 B); source granule = slot ^ ((subrow>>1)&3) ----
    const int lsub = lane >> 2;                    // 0..15
    const int gsrc = (lane & 3) ^ ((lane >> 3) & 3);

    // A: wave w stages rows [w*16, +16): one GLDS per thread per iter
    int arow = r0 + wid * 16 + lsub; if (arow > MROWS - 1) arow = MROWS - 1;
    const int aoff = arow * CN + gsrc * 8;
    const int adst = wid * 1024;                   // within A region

    // B: two chunks j=0,1: cols c0 + j*128 + w*16 + lsub (clamped)
    int boff[2];
#pragma unroll
    for (int j = 0; j < 2; ++j) {
        int col = c0 + j * 128 + wid * 16 + lsub;
        if (col > NSUP - 1) col = NSUP - 1;
        boff[j] = col * CN + gsrc * 8;
    }
    const int bdst0 = 8192 + wid * 1024;           // within buf (B starts at +8 KB)

    const int q_ = lane >> 4;      // k-granule (0..3, 8 elems each)
    const int lr = lane & 15;      // row/col within 16x16 tile
    const int sl = (q_ ^ ((lr >> 1) & 3)) * 8;     // swizzled read slot offset

    // ---- prologue: stage tile 0 into buf0, full drain ----
    GLDS(qptr + aoff, smem + adst);
    GLDS(sptr + boff[0], smem + bdst0);
    GLDS(sptr + boff[1], smem + bdst0 + 8192);
    __syncthreads();

    int p = 0;
    for (int k0 = 0; k0 < CN; k0 += BK) {
        // 1) prefetch next tile into the other buffer (no wait!)
        if (k0 + BK < CN) {
            char* nb = smem + (p ^ 1) * 24576;
            GLDS(qptr + aoff + k0 + BK, nb + adst);
            GLDS(sptr + boff[0] + k0 + BK, nb + bdst0);
            GLDS(sptr + boff[1] + k0 + BK, nb + bdst0 + 8192);
        }
        // 2) compute on current buffer
        const unsigned short* Alds = (const unsigned short*)(smem + p * 24576);
        const unsigned short* Blds = Alds + 4096;          // +8 KB
        bf16x8 af[4];
#pragma unroll
        for (int mt = 0; mt < 4; ++mt)
            af[mt] = *(const bf16x8*)(Alds + (h * 64 + mt * 16 + lr) * 32 + sl);
#pragma unroll
        for (int nt = 0; nt < 4; ++nt) {
            bf16x8 bfr = *(const bf16x8*)(Blds + (colq * 64 + nt * 16 + lr) * 32 + sl);
#pragma unroll
            for (int mt = 0; mt < 4; ++mt)
                acc[mt][nt] = __builtin_amdgcn_mfma_f32_16x16x32_bf16(af[mt], bfr, acc[mt][nt], 0, 0, 0);
        }
        // 3) single barrier: drains the prefetch (landed during compute) and
        //    protects buf[p] from next iteration's prefetch overwrite
        __syncthreads();
        p ^= 1;
    }

    // -------- epilogue: per-mt, 32 C-rows (both halves) via LDS -----------
    // FULLY UNROLLED over mt (runtime acc[] index -> scratch spill; see R2).
    const int erow = t >> 4;        // 0..31 (Cst row)
    const int es   = t & 15;        // 16 scanners per row (within one wave)
#define CE(a, b) { float hi_ = fmaxf(a, b), lo_ = fminf(a, b); a = hi_; b = lo_; }
#pragma unroll
    for (int mt = 0; mt < 4; ++mt) {
        __syncthreads();
#pragma unroll
        for (int nt = 0; nt < 4; ++nt)
#pragma unroll
            for (int e = 0; e < 4; ++e)
                Cst[(h * 16 + q_ * 4 + e) * CST + colq * 64 + nt * 16 + lr] = acc[mt][nt][e];
        __syncthreads();

        float t0 = -3.4e38f, t1 = -3.4e38f, t2 = -3.4e38f, t3 = -3.4e38f, t4 = -3.4e38f;
#pragma unroll
        for (int i = 0; i < 16; ++i) {
            int col = es + 16 * i;
            float v = (c0 + col < NSUP) ? Cst[erow * CST + col] : -3.4e38f;
            float hi;
            hi = fmaxf(t0, v); v = fminf(t0, v); t0 = hi;
            hi = fmaxf(t1, v); v = fminf(t1, v); t1 = hi;
            hi = fmaxf(t2, v); v = fminf(t2, v); t2 = hi;
            hi = fmaxf(t3, v); v = fminf(t3, v); t3 = hi;
            hi = fmaxf(t4, v); v = fminf(t4, v); t4 = hi;
        }
#pragma unroll
        for (int d = 1; d < 16; d <<= 1) {
            float b0 = __shfl_xor(t0, d, 64);
            float b1 = __shfl_xor(t1, d, 64);
            float b2 = __shfl_xor(t2, d, 64);
            float b3 = __shfl_xor(t3, d, 64);
            float b4 = __shfl_xor(t4, d, 64);
            t0 = fmaxf(t0, b4); t1 = fmaxf(t1, b3); t2 = fmaxf(t2, b2);
            t3 = fmaxf(t3, b1); t4 = fmaxf(t4, b0);
            CE(t0, t1); CE(t2, t3);
            CE(t1, t2); CE(t3, t4);
            CE(t0, t1); CE(t2, t3);
            CE(t1, t2); CE(t3, t4);
            CE(t0, t1); CE(t2, t3);
        }
        if (es == 0) {
            int patch = r0 + (erow >> 4) * 64 + mt * 16 + (erow & 15);
            if (patch < MROWS) {
                float* pp = part + ((size_t)(bg * MROWS + patch) * 2 + nc) * 5;
                pp[0] = t0; pp[1] = t1; pp[2] = t2; pp[3] = t3; pp[4] = t4;
            }
        }
    }
#undef CE
}

// ---------------------------------------------------------------------------
// Merge: one wave per (b,qi,g) = 750 waves. Top-5 of the union of the two
// sorted per-chunk top-5s, mean, wave-reduce over 100 patches, direct store.
// ---------------------------------------------------------------------------
__global__ __launch_bounds__(256) void merge_kernel(const float* __restrict__ part,
                                                    float* __restrict__ out) {
    int w    = (blockIdx.x * 256 + threadIdx.x) >> 6;
    int lane = threadIdx.x & 63;
    if (w >= 750) return;
    int b  = w / 375, r = w % 375;
    int qi = r / 5,   g = r % 5;
    int bg = b * 5 + g;

    float sum = 0.f;
    for (int p = lane; p < HWN; p += 64) {
        int row = qi * HWN + p;
        const float* pp = part + (size_t)(bg * MROWS + row) * 10;
        float t0 = -3.4e38f, t1 = -3.4e38f, t2 = -3.4e38f, t3 = -3.4e38f, t4 = -3.4e38f;
#pragma unroll
        for (int j = 0; j < 10; ++j) {
            float v = pp[j], hi;
            hi = fmaxf(t0, v); v = fminf(t0, v); t0 = hi;
            hi = fmaxf(t1, v); v = fminf(t1, v); t1 = hi;
            hi = fmaxf(t2, v); v = fminf(t2, v); t2 = hi;
            hi = fmaxf(t3, v); v = fminf(t3, v); t3 = hi;
            hi = fmaxf(t4, v); v = fminf(t4, v); t4 = hi;
        }
        sum += (t0 + t1 + t2 + t3 + t4) * 0.2f;
    }
#pragma unroll
    for (int off = 32; off > 0; off >>= 1)
        sum += __shfl_xor(sum, off, 64);
    if (lane == 0) out[w] = sum;        // out[(b*75+qi)*5+g] == out[w]
}

extern "C" void kernel_launch(void* const* d_in, const int* in_sizes, int n_in,
                              void* d_out, int out_size, void* d_ws, size_t ws_size,
                              hipStream_t stream) {
    const float* in1 = (const float*)d_in[0];
    const float* in2 = (const float*)d_in[1];
    float* out = (float*)d_out;

    unsigned short* qbf  = (unsigned short*)d_ws;            // 15000*640 bf16 = 19.2 MB
    unsigned short* sbf  = qbf + (size_t)NQD * CN;           //  5000*640 bf16 =  6.4 MB
    float*          part = (float*)(sbf + (size_t)NSD * CN); // 750000 fp32 = 3 MB

    prep_kernel<<<dim3(NDESC / 4), 256, 0, stream>>>(in1, in2, qbf, sbf);
    mfma_kernel<<<dim3(1200), 512, 0, stream>>>(qbf, sbf, part);   // XCD-clustered, pipelined
    merge_kernel<<<dim3(188), 256, 0, stream>>>(part, out);        // 750 waves
}